// Round 7
// baseline (256.378 us; speedup 1.0000x reference)
//
#include <hip/hip_runtime.h>

typedef __attribute__((ext_vector_type(8))) short short8_t;
typedef __attribute__((ext_vector_type(4))) short short4_t;
typedef __attribute__((ext_vector_type(4))) float float4_t;
typedef __attribute__((ext_vector_type(2))) unsigned int uint2_t;

__device__ __forceinline__ unsigned short f2bf(float f) {
    unsigned u = __builtin_bit_cast(unsigned, f);
    u += 0x7FFFu + ((u >> 16) & 1u);
    return (unsigned short)(u >> 16);
}

// two f32 -> packed 2x bf16 (RNE) in one instruction
__device__ __forceinline__ unsigned pk_bf16(float a, float b) {
    unsigned r;
    asm("v_cvt_pk_bf16_f32 %0, %1, %2" : "=v"(r) : "v"(a), "v"(b));
    return r;
}

// 8 f32 (two float4) -> short8 bf16
__device__ __forceinline__ short8_t pk8(float4_t a, float4_t b) {
    union { unsigned u[4]; short8_t s; } r;
    r.u[0] = pk_bf16(a[0], a[1]); r.u[1] = pk_bf16(a[2], a[3]);
    r.u[2] = pk_bf16(b[0], b[1]); r.u[3] = pk_bf16(b[2], b[3]);
    return r.s;
}

#define MFMA(A, B, C) __builtin_amdgcn_mfma_f32_16x16x32_bf16((A), (B), (C), 0, 0, 0)

// ---------------------------------------------------------------------------
// Kernel 1 (v2, unchanged): per-head Lorentz FC projections.
// grid = (64 row-tiles of 64, 8 heads, 3 mats). block = 256, 4 blocks/CU.
// ---------------------------------------------------------------------------
__global__ __launch_bounds__(256, 4) void k_proj(
    const float* __restrict__ x,
    const float* __restrict__ Wq, const float* __restrict__ bq,
    const float* __restrict__ Wk, const float* __restrict__ bk,
    const float* __restrict__ Wv, const float* __restrict__ bv,
    unsigned short* __restrict__ Qs, unsigned short* __restrict__ Kb,
    unsigned short* __restrict__ Vt)
{
    __shared__ __align__(16) unsigned char lds[19456];
    unsigned short* Xs  = (unsigned short*)lds;            // [64][136] bf16 (17408)
    unsigned short* Ot  = (unsigned short*)lds;            // reuse: [64][136] bf16
    unsigned short* OtT = (unsigned short*)lds;            // reuse: [128][72] bf16
    float*          ssqB = (float*)(lds + 18432);          // [64][4]

    const int tid = threadIdx.x;
    const int m0  = blockIdx.x * 64;
    const int h   = blockIdx.y;
    const int mat = blockIdx.z;
    const float* W  = (mat == 0) ? Wq : ((mat == 1) ? Wk : Wv);
    const float* bb = (mat == 0) ? bq : ((mat == 1) ? bk : bv);

    const int w = tid >> 6, lane = tid & 63, li = lane & 15, lg = lane >> 4;

    // issue W fragment loads first (long-latency, direct f32 from global/L2)
    const int e = w * 32 + li;            // rows e and e+16 used below
    float4_t wf[8][2];
    #pragma unroll
    for (int ni = 0; ni < 2; ni++) {
        int ee = e + ni * 16;
        const float* wp = W + (h * 127 + (ee < 127 ? ee : 0)) * 128 + lg * 8;
        #pragma unroll
        for (int kk = 0; kk < 4; kk++) {
            float4_t a = *(const float4_t*)(wp + kk * 32);
            float4_t b2 = *(const float4_t*)(wp + kk * 32 + 4);
            if (ee >= 127) { a = (float4_t){0.f,0.f,0.f,0.f}; b2 = (float4_t){0.f,0.f,0.f,0.f}; }
            wf[ni * 4 + kk][0] = a; wf[ni * 4 + kk][1] = b2;
        }
    }

    // stage X tile (64 x 128, fp32 -> bf16)
    #pragma unroll
    for (int p = 0; p < 8; p++) {
        int r = p * 8 + (tid >> 5), c = (tid & 31) * 4;
        float4_t v = *(const float4_t*)(x + (m0 + r) * 128 + c);
        uint2_t u; u[0] = pk_bf16(v[0], v[1]); u[1] = pk_bf16(v[2], v[3]);
        *(uint2_t*)(Xs + r * 136 + c) = u;
    }
    __syncthreads();   // Xs ready

    short8_t Bf[8];
    #pragma unroll
    for (int f = 0; f < 8; f++) Bf[f] = pk8(wf[f][0], wf[f][1]);

    float4_t acc[4][2];
    #pragma unroll
    for (int i = 0; i < 4; i++)
        #pragma unroll
        for (int j = 0; j < 2; j++) acc[i][j] = (float4_t){0.f, 0.f, 0.f, 0.f};

    #pragma unroll
    for (int kk = 0; kk < 4; kk++) {
        #pragma unroll
        for (int mi = 0; mi < 4; mi++) {
            short8_t A = *(short8_t*)(Xs + (mi * 16 + li) * 136 + kk * 32 + lg * 8);
            acc[mi][0] = MFMA(A, Bf[kk],     acc[mi][0]);
            acc[mi][1] = MFMA(A, Bf[4 + kk], acc[mi][1]);
        }
    }
    // bias
    #pragma unroll
    for (int ni = 0; ni < 2; ni++) {
        int ee = e + ni * 16;
        float bvv = (ee < 127) ? bb[h * 127 + ee] : 0.0f;
        #pragma unroll
        for (int mi = 0; mi < 4; mi++)
            #pragma unroll
            for (int r = 0; r < 4; r++) acc[mi][ni][r] += bvv;
    }
    // per-row sum of squares of space components
    #pragma unroll
    for (int mi = 0; mi < 4; mi++) {
        #pragma unroll
        for (int r = 0; r < 4; r++) {
            float s = acc[mi][0][r] * acc[mi][0][r] + acc[mi][1][r] * acc[mi][1][r];
            s += __shfl_xor(s, 1);  s += __shfl_xor(s, 2);
            s += __shfl_xor(s, 4);  s += __shfl_xor(s, 8);
            if (li == 0) ssqB[(mi * 16 + lg * 4 + r) * 4 + w] = s;
        }
    }
    __syncthreads();   // ssqB ready AND all Xs reads complete -> safe to reuse

    if (mat < 2) {
        #pragma unroll
        for (int mi = 0; mi < 4; mi++)
            #pragma unroll
            for (int ni = 0; ni < 2; ni++) {
                int ee = e + ni * 16;
                if (ee < 127) {
                    #pragma unroll
                    for (int r = 0; r < 4; r++)
                        Ot[(mi * 16 + lg * 4 + r) * 136 + 1 + ee] = f2bf(acc[mi][ni][r]);
                }
            }
        if (tid < 64) {
            float s = ssqB[tid * 4] + ssqB[tid * 4 + 1] + ssqB[tid * 4 + 2] + ssqB[tid * 4 + 3];
            float t = sqrtf(1.0f + s);
            Ot[tid * 136] = f2bf(mat == 0 ? -t : t);
        }
        __syncthreads();
        unsigned short* dst = ((mat == 0) ? Qs : Kb) + (h * 4096 + m0) * 128;
        #pragma unroll
        for (int p = 0; p < 4; p++) {
            int r = p * 16 + (tid >> 4), c = (tid & 15) * 8;
            *(short8_t*)(dst + r * 128 + c) = *(short8_t*)(Ot + r * 136 + c);
        }
    } else {
        #pragma unroll
        for (int mi = 0; mi < 4; mi++)
            #pragma unroll
            for (int ni = 0; ni < 2; ni++) {
                int ee = e + ni * 16;
                if (ee < 127) {
                    uint2_t u;
                    u[0] = pk_bf16(acc[mi][ni][0], acc[mi][ni][1]);
                    u[1] = pk_bf16(acc[mi][ni][2], acc[mi][ni][3]);
                    *(uint2_t*)(OtT + (1 + ee) * 72 + mi * 16 + lg * 4) = u;
                }
            }
        if (tid < 64) {
            float s = ssqB[tid * 4] + ssqB[tid * 4 + 1] + ssqB[tid * 4 + 2] + ssqB[tid * 4 + 3];
            OtT[tid] = f2bf(sqrtf(1.0f + s));
        }
        __syncthreads();
        int b = m0 >> 10, n0 = m0 & 1023;
        unsigned short* dst = Vt + (h * 4 + b) * 131072 + n0;
        #pragma unroll
        for (int p = 0; p < 4; p++) {
            int d = p * 32 + (tid >> 3), nc = (tid & 7) * 8;
            *(short8_t*)(dst + d * 1024 + nc) = *(short8_t*)(OtT + d * 72 + nc);
        }
    }
}

// ---------------------------------------------------------------------------
// Kernel 2 (v4): fused Lorentz attention, SPLIT-KV x2 for 2x occupancy.
// grid = 1024 blocks = (hb:32) x (qt:16) x (half:2), XCD-swizzled (hb&7).
// block = 256 (4 waves, wave owns 16 q-rows); each block does HALF the KV
// (8 tiles of 64). Single-buffered K/V LDS with XOR-swizzle (40.0 KB ->
// 4 blocks/CU = 4 waves/SIMD); reg-prefetch of tile t+1 before tile t's
// compute; 2 barriers/tile; setprio around MFMA.
// KEY ALGEBRA: Lorentz-midpoint normalize is scale-invariant in mid, so
// the softmax denominator cancels -> no lsum anywhere; halves merge by
// plain summation (beta==1; generic beta stores log2-max m for merge).
// Epilogue dumps raw amid (+m) to workspace; k_merge finishes.
// ---------------------------------------------------------------------------
__global__ __launch_bounds__(256, 4) void k_attn(
    const unsigned short* __restrict__ Qsg, const unsigned short* __restrict__ Kb,
    const unsigned short* __restrict__ Vt,
    const float* __restrict__ beta, const float* __restrict__ gamma,
    float* __restrict__ part)
{
    __shared__ __align__(16) unsigned char lds[40960];
    char* Kl = (char*)lds;             // [64][128] bf16, XOR-swizzled (16384)
    char* Vl = (char*)lds + 16384;     // [128][64] bf16, XOR-swizzled (16384)
    char* Pl = (char*)lds + 32768;     // [64][64]  bf16, XOR-swizzled (8192)
    float* pw = (float*)lds;           // epilogue reuse: [4][16][132] f32

    const int tid = threadIdx.x, w = tid >> 6, lane = tid & 63;
    const int li = lane & 15, lg = lane >> 4;

    // decode: xcd = bid&7; all 32 blocks of one (h,b) share an XCD
    const int bid = blockIdx.x;
    const int hb = bid & 31;
    const int qt = (bid >> 5) & 15;
    const int half = (bid >> 9) & 1;
    const int h = hb >> 2, b = hb & 3;
    const int q0 = qt * 64;

    const unsigned short* Qp = Qsg + (h * 4096 + b * 1024) * 128;
    const unsigned short* Kp = Kb  + (h * 4096 + b * 1024) * 128;
    const unsigned short* Vp = Vt  + (h * 4 + b) * 131072;
    const float bet = beta[h];
    const bool beta1 = (bet == 1.0f);
    (void)gamma;

    // per-thread staging (global src, swizzled LDS dst)
    const int kr = tid >> 4, kc16 = (tid & 15) * 16;          // K row, 16B chunk
    const int vd = tid >> 3, vc16 = (tid & 7) * 16;           // V row, 16B chunk
    const int kwb = (kr * 256 + kc16) ^ ((kr & 7) << 4);      // K write byte
    const int vwb = (vd * 128 + vc16) ^ ((vd & 7) << 4);      // V write byte
    const unsigned short* Kld = Kp + (half * 512 + kr) * 128 + (tid & 15) * 8;
    const unsigned short* Vld = Vp + vd * 1024 + half * 512 + (tid & 7) * 8;

    // per-lane read bases (swizzle XOR is lane-constant)
    const int lxor = (li & 7) << 4;
    const int krb = (li * 256 + lg * 16) ^ lxor;              // + jf*4096 + kk*64
    const int vrb = (li * 128 + lg * 16) ^ lxor;              // + df*2048 + kk2*64
    const int prb = ((w * 16 + li) * 128 + lg * 16) ^ lxor;   // + kk2*64
    const int pwb = ((w * 16 + li) * 128 + lg * 8) ^ lxor;    // + jf*32

    // persistent Q fragments (16 q-rows per wave, B-operand layout)
    short8_t qf[4];
    const int qrow = q0 + w * 16 + li;
    #pragma unroll
    for (int kk = 0; kk < 4; kk++)
        qf[kk] = *(const short8_t*)(Qp + qrow * 128 + kk * 32 + lg * 8);

    float4_t amid[8];
    #pragma unroll
    for (int df = 0; df < 8; df++) amid[df] = (float4_t){0.f, 0.f, 0.f, 0.f};
    float m = beta1 ? 0.0f : -INFINITY;   // log2-domain running max (generic)

    short8_t kreg[4], vreg[4];
    // prologue: stage tile 0 of this half
    #pragma unroll
    for (int p = 0; p < 4; p++) {
        kreg[p] = *(const short8_t*)(Kld + p * 2048);
        vreg[p] = *(const short8_t*)(Vld + p * 32768);
    }
    #pragma unroll
    for (int p = 0; p < 4; p++) {
        *(short8_t*)(Kl + p * 4096 + kwb) = kreg[p];
        *(short8_t*)(Vl + p * 4096 + vwb) = vreg[p];
    }
    __syncthreads();

    for (int t = 0; t < 8; t++) {
        // issue next tile's global loads NOW — land during this tile's compute
        if (t < 7) {
            const int j0n = (t + 1) * 64;
            #pragma unroll
            for (int p = 0; p < 4; p++) {
                kreg[p] = *(const short8_t*)(Kld + j0n * 128 + p * 2048);
                vreg[p] = *(const short8_t*)(Vld + p * 32768 + j0n);
            }
        }
        __builtin_amdgcn_sched_barrier(0);   // keep loads issued up here

        // S^T = K . Qsgn
        float4_t as[4];
        #pragma unroll
        for (int jf = 0; jf < 4; jf++) as[jf] = (float4_t){0.f, 0.f, 0.f, 0.f};
        __builtin_amdgcn_s_setprio(1);
        #pragma unroll
        for (int kk = 0; kk < 4; kk++) {
            #pragma unroll
            for (int jf = 0; jf < 4; jf++) {
                short8_t A = *(short8_t*)(Kl + ((jf * 4096 + kk * 64) ^ krb));
                as[jf] = MFMA(A, qf[kk], as[jf]);
            }
        }
        __builtin_amdgcn_s_setprio(0);

        if (beta1) {
            // beta==1: P = 1/(z+sqrt(z^2-1)) in (0,1] — bounded, no max
            #pragma unroll
            for (int jf = 0; jf < 4; jf++) {
                float p[4];
                #pragma unroll
                for (int r = 0; r < 4; r++) {
                    float z = fmaxf(-as[jf][r], 1.0f + 1e-6f);
                    float wv = z + __builtin_amdgcn_sqrtf(__builtin_fmaf(z, z, -1.0f));
                    p[r] = __builtin_amdgcn_rcpf(wv);
                }
                uint2_t u; u[0] = pk_bf16(p[0], p[1]); u[1] = pk_bf16(p[2], p[3]);
                *(uint2_t*)(Pl + ((jf * 32) ^ pwb)) = u;
            }
        } else {
            // generic beta: log2-domain, defer-max; amid stays UNNORMALIZED
            float s2[16];
            float tm = -INFINITY;
            #pragma unroll
            for (int jf = 0; jf < 4; jf++) {
                #pragma unroll
                for (int r = 0; r < 4; r++) {
                    float z = fmaxf(-as[jf][r], 1.0f + 1e-6f);
                    float wv = z + __builtin_amdgcn_sqrtf(__builtin_fmaf(z, z, -1.0f));
                    float s = -bet * __builtin_amdgcn_logf(wv);
                    s2[jf * 4 + r] = s;
                    tm = fmaxf(tm, s);
                }
            }
            tm = fmaxf(tm, __shfl_xor(tm, 16));
            tm = fmaxf(tm, __shfl_xor(tm, 32));
            if (__any(tm > m + 8.0f)) {
                float mn = fmaxf(m, tm);
                float scale = __builtin_amdgcn_exp2f(m - mn);
                #pragma unroll
                for (int df = 0; df < 8; df++)
                    #pragma unroll
                    for (int r = 0; r < 4; r++) amid[df][r] *= scale;
                m = mn;
            }
            #pragma unroll
            for (int jf = 0; jf < 4; jf++) {
                float p0 = __builtin_amdgcn_exp2f(s2[jf * 4 + 0] - m);
                float p1 = __builtin_amdgcn_exp2f(s2[jf * 4 + 1] - m);
                float p2 = __builtin_amdgcn_exp2f(s2[jf * 4 + 2] - m);
                float p3 = __builtin_amdgcn_exp2f(s2[jf * 4 + 3] - m);
                uint2_t u; u[0] = pk_bf16(p0, p1); u[1] = pk_bf16(p2, p3);
                *(uint2_t*)(Pl + ((jf * 32) ^ pwb)) = u;
            }
        }
        // P writes are wave-local: drain LDS, fence the scheduler
        asm volatile("s_waitcnt lgkmcnt(0)" ::: "memory");
        __builtin_amdgcn_sched_barrier(0);

        // PV: mid^T[d,i] += V^T[d,j] * P^T[j,i]
        __builtin_amdgcn_s_setprio(1);
        #pragma unroll
        for (int kk2 = 0; kk2 < 2; kk2++) {
            short8_t Bp = *(short8_t*)(Pl + ((kk2 * 64) ^ prb));
            #pragma unroll
            for (int df = 0; df < 8; df++) {
                short8_t A = *(short8_t*)(Vl + ((df * 2048 + kk2 * 64) ^ vrb));
                amid[df] = MFMA(A, Bp, amid[df]);
            }
        }
        __builtin_amdgcn_s_setprio(0);

        // restage the single buffer (loads landed during compute)
        if (t < 7) {
            __syncthreads();   // A: all waves' K/V/P reads done
            #pragma unroll
            for (int p = 0; p < 4; p++) {
                *(short8_t*)(Kl + p * 4096 + kwb) = kreg[p];
                *(short8_t*)(Vl + p * 4096 + vwb) = vreg[p];
            }
            __syncthreads();   // B: new tile visible
        }
    }

    // epilogue: dump raw partial (amid, m) — no normalize (denominator
    // cancels in the midpoint rescale; done in k_merge)
    __syncthreads();   // everyone done with Kl/Vl/Pl -> reuse as pw
    #pragma unroll
    for (int df = 0; df < 8; df++) {
        #pragma unroll
        for (int r = 0; r < 4; r++)
            pw[w * 2112 + li * 132 + df * 16 + lg * 4 + r] = amid[df][r];
    }
    if (lg == 0) pw[w * 2112 + li * 132 + 128] = m;
    asm volatile("s_waitcnt lgkmcnt(0)" ::: "memory");
    __builtin_amdgcn_sched_barrier(0);

    // coalesced dump: 16 rows x 132 f32 per wave
    float* pb = part + (size_t)(((half * 8 + h) * 4 + b) * 1024 + q0 + w * 16) * 132;
    #pragma unroll
    for (int it = 0; it < 8; it++) {
        int idx = it * 64 + lane;                 // 0..511
        int row = idx >> 5, c4 = idx & 31;        // cols 0..127
        *(float4_t*)(pb + row * 132 + c4 * 4) =
            *(float4_t*)(pw + w * 2112 + row * 132 + c4 * 4);
    }
    if (lane < 16)
        *(float4_t*)(pb + lane * 132 + 128) =
            *(float4_t*)(pw + w * 2112 + lane * 132 + 128);
}

// ---------------------------------------------------------------------------
// Kernel 3: merge halves + Lorentz-midpoint rescale + concat + time coord.
// grid = 1024 blocks x 256 thr; wave per (b,n) row; lane = (h:3)(sub:3).
// ---------------------------------------------------------------------------
__global__ __launch_bounds__(256) void k_merge(const float* __restrict__ part,
                                               float* __restrict__ out)
{
    const int tid = threadIdx.x, w = tid >> 6, lane = tid & 63;
    const int h = lane >> 3, sub = lane & 7;
    const int row = blockIdx.x * 4 + w;           // 0..4095
    const int b = row >> 10, n = row & 1023;

    const float* p0 = part + (size_t)(((0 * 8 + h) * 4 + b) * 1024 + n) * 132;
    const float* p1 = part + (size_t)(((1 * 8 + h) * 4 + b) * 1024 + n) * 132;

    float4_t a0[4], a1[4];
    #pragma unroll
    for (int q = 0; q < 4; q++) {
        a0[q] = *(const float4_t*)(p0 + sub * 16 + q * 4);
        a1[q] = *(const float4_t*)(p1 + sub * 16 + q * 4);
    }
    float m0 = p0[128], m1 = p1[128];
    float mN = fmaxf(m0, m1);
    float s0 = __builtin_amdgcn_exp2f(m0 - mN);
    float s1 = __builtin_amdgcn_exp2f(m1 - mN);

    float4_t acc[4];
    float ssq = 0.0f;
    #pragma unroll
    for (int q = 0; q < 4; q++) {
        #pragma unroll
        for (int e2 = 0; e2 < 4; e2++) {
            float v = a0[q][e2] * s0 + a1[q][e2] * s1;
            acc[q][e2] = v;
            ssq += v * v;
        }
    }
    ssq += __shfl_xor(ssq, 1);
    ssq += __shfl_xor(ssq, 2);
    ssq += __shfl_xor(ssq, 4);
    float t = __shfl(acc[0][0], lane & 56);       // d=0 value of this head
    float denom = fmaxf(2.0f * t * t - ssq, 1e-6f);
    float rs = 1.0f / sqrtf(denom);

    // time coordinate: sum (t_h * rs_h)^2 over heads
    float th2 = (t * rs) * (t * rs);
    th2 += __shfl_xor(th2, 8);
    th2 += __shfl_xor(th2, 16);
    th2 += __shfl_xor(th2, 32);
    float timec = sqrtf(fmaxf(th2 - 7.0f, 1e-6f));

    float* orow = out + (size_t)row * 1017;
    if (lane == 0) orow[0] = timec;
    #pragma unroll
    for (int k = 0; k < 16; k++) {
        int d = sub * 16 + k;
        if (d > 0) orow[h * 127 + d] = acc[k >> 2][k & 3] * rs;
    }
}

extern "C" void kernel_launch(void* const* d_in, const int* in_sizes, int n_in,
                              void* d_out, int out_size, void* d_ws, size_t ws_size,
                              hipStream_t stream)
{
    const float* x    = (const float*)d_in[0];
    const float* Wq   = (const float*)d_in[1];
    const float* bq   = (const float*)d_in[2];
    const float* Wk   = (const float*)d_in[3];
    const float* bk   = (const float*)d_in[4];
    const float* Wv   = (const float*)d_in[5];
    const float* bv   = (const float*)d_in[6];
    const float* beta = (const float*)d_in[7];
    const float* gam  = (const float*)d_in[8];
    float* out = (float*)d_out;

    unsigned char* ws = (unsigned char*)d_ws;
    unsigned short* Qs = (unsigned short*)(ws);              //  8 MB
    unsigned short* Kb = (unsigned short*)(ws + 8388608);    //  8 MB
    unsigned short* Vt = (unsigned short*)(ws + 16777216);   //  8 MB
    float*          pt = (float*)(ws + 25165824);            // 34.6 MB partials

    k_proj<<<dim3(64, 8, 3), 256, 0, stream>>>(x, Wq, bq, Wk, bk, Wv, bv, Qs, Kb, Vt);
    k_attn<<<dim3(1024), 256, 0, stream>>>(Qs, Kb, Vt, beta, gam, pt);
    k_merge<<<dim3(1024), 256, 0, stream>>>(pt, out);
}

// Round 9
// 163.195 us; speedup vs baseline: 1.5710x; 1.5710x over previous
//
#include <hip/hip_runtime.h>

typedef __attribute__((ext_vector_type(8))) short short8_t;
typedef __attribute__((ext_vector_type(4))) short short4_t;
typedef __attribute__((ext_vector_type(4))) float float4_t;
typedef __attribute__((ext_vector_type(2))) unsigned int uint2_t;

__device__ __forceinline__ unsigned short f2bf(float f) {
    unsigned u = __builtin_bit_cast(unsigned, f);
    u += 0x7FFFu + ((u >> 16) & 1u);
    return (unsigned short)(u >> 16);
}

// two f32 -> packed 2x bf16 (RNE) in one instruction
__device__ __forceinline__ unsigned pk_bf16(float a, float b) {
    unsigned r;
    asm("v_cvt_pk_bf16_f32 %0, %1, %2" : "=v"(r) : "v"(a), "v"(b));
    return r;
}

// 8 f32 (two float4) -> short8 bf16
__device__ __forceinline__ short8_t pk8(float4_t a, float4_t b) {
    union { unsigned u[4]; short8_t s; } r;
    r.u[0] = pk_bf16(a[0], a[1]); r.u[1] = pk_bf16(a[2], a[3]);
    r.u[2] = pk_bf16(b[0], b[1]); r.u[3] = pk_bf16(b[2], b[3]);
    return r.s;
}

#define MFMA(A, B, C) __builtin_amdgcn_mfma_f32_16x16x32_bf16((A), (B), (C), 0, 0, 0)

// ---------------------------------------------------------------------------
// Kernel 1 (v2, unchanged): per-head Lorentz FC projections.
// grid = (64 row-tiles of 64, 8 heads, 3 mats). block = 256, 4 blocks/CU.
// ---------------------------------------------------------------------------
__global__ __launch_bounds__(256, 4) void k_proj(
    const float* __restrict__ x,
    const float* __restrict__ Wq, const float* __restrict__ bq,
    const float* __restrict__ Wk, const float* __restrict__ bk,
    const float* __restrict__ Wv, const float* __restrict__ bv,
    unsigned short* __restrict__ Qs, unsigned short* __restrict__ Kb,
    unsigned short* __restrict__ Vt)
{
    __shared__ __align__(16) unsigned char lds[19456];
    unsigned short* Xs  = (unsigned short*)lds;            // [64][136] bf16 (17408)
    unsigned short* Ot  = (unsigned short*)lds;            // reuse: [64][136] bf16
    unsigned short* OtT = (unsigned short*)lds;            // reuse: [128][72] bf16
    float*          ssqB = (float*)(lds + 18432);          // [64][4]

    const int tid = threadIdx.x;
    const int m0  = blockIdx.x * 64;
    const int h   = blockIdx.y;
    const int mat = blockIdx.z;
    const float* W  = (mat == 0) ? Wq : ((mat == 1) ? Wk : Wv);
    const float* bb = (mat == 0) ? bq : ((mat == 1) ? bk : bv);

    const int w = tid >> 6, lane = tid & 63, li = lane & 15, lg = lane >> 4;

    // issue W fragment loads first (long-latency, direct f32 from global/L2)
    const int e = w * 32 + li;            // rows e and e+16 used below
    float4_t wf[8][2];
    #pragma unroll
    for (int ni = 0; ni < 2; ni++) {
        int ee = e + ni * 16;
        const float* wp = W + (h * 127 + (ee < 127 ? ee : 0)) * 128 + lg * 8;
        #pragma unroll
        for (int kk = 0; kk < 4; kk++) {
            float4_t a = *(const float4_t*)(wp + kk * 32);
            float4_t b2 = *(const float4_t*)(wp + kk * 32 + 4);
            if (ee >= 127) { a = (float4_t){0.f,0.f,0.f,0.f}; b2 = (float4_t){0.f,0.f,0.f,0.f}; }
            wf[ni * 4 + kk][0] = a; wf[ni * 4 + kk][1] = b2;
        }
    }

    // stage X tile (64 x 128, fp32 -> bf16)
    #pragma unroll
    for (int p = 0; p < 8; p++) {
        int r = p * 8 + (tid >> 5), c = (tid & 31) * 4;
        float4_t v = *(const float4_t*)(x + (m0 + r) * 128 + c);
        uint2_t u; u[0] = pk_bf16(v[0], v[1]); u[1] = pk_bf16(v[2], v[3]);
        *(uint2_t*)(Xs + r * 136 + c) = u;
    }
    __syncthreads();   // Xs ready

    short8_t Bf[8];
    #pragma unroll
    for (int f = 0; f < 8; f++) Bf[f] = pk8(wf[f][0], wf[f][1]);

    float4_t acc[4][2];
    #pragma unroll
    for (int i = 0; i < 4; i++)
        #pragma unroll
        for (int j = 0; j < 2; j++) acc[i][j] = (float4_t){0.f, 0.f, 0.f, 0.f};

    #pragma unroll
    for (int kk = 0; kk < 4; kk++) {
        #pragma unroll
        for (int mi = 0; mi < 4; mi++) {
            short8_t A = *(short8_t*)(Xs + (mi * 16 + li) * 136 + kk * 32 + lg * 8);
            acc[mi][0] = MFMA(A, Bf[kk],     acc[mi][0]);
            acc[mi][1] = MFMA(A, Bf[4 + kk], acc[mi][1]);
        }
    }
    // bias
    #pragma unroll
    for (int ni = 0; ni < 2; ni++) {
        int ee = e + ni * 16;
        float bvv = (ee < 127) ? bb[h * 127 + ee] : 0.0f;
        #pragma unroll
        for (int mi = 0; mi < 4; mi++)
            #pragma unroll
            for (int r = 0; r < 4; r++) acc[mi][ni][r] += bvv;
    }
    // per-row sum of squares of space components
    #pragma unroll
    for (int mi = 0; mi < 4; mi++) {
        #pragma unroll
        for (int r = 0; r < 4; r++) {
            float s = acc[mi][0][r] * acc[mi][0][r] + acc[mi][1][r] * acc[mi][1][r];
            s += __shfl_xor(s, 1);  s += __shfl_xor(s, 2);
            s += __shfl_xor(s, 4);  s += __shfl_xor(s, 8);
            if (li == 0) ssqB[(mi * 16 + lg * 4 + r) * 4 + w] = s;
        }
    }
    __syncthreads();   // ssqB ready AND all Xs reads complete -> safe to reuse

    if (mat < 2) {
        #pragma unroll
        for (int mi = 0; mi < 4; mi++)
            #pragma unroll
            for (int ni = 0; ni < 2; ni++) {
                int ee = e + ni * 16;
                if (ee < 127) {
                    #pragma unroll
                    for (int r = 0; r < 4; r++)
                        Ot[(mi * 16 + lg * 4 + r) * 136 + 1 + ee] = f2bf(acc[mi][ni][r]);
                }
            }
        if (tid < 64) {
            float s = ssqB[tid * 4] + ssqB[tid * 4 + 1] + ssqB[tid * 4 + 2] + ssqB[tid * 4 + 3];
            float t = sqrtf(1.0f + s);
            Ot[tid * 136] = f2bf(mat == 0 ? -t : t);
        }
        __syncthreads();
        unsigned short* dst = ((mat == 0) ? Qs : Kb) + (h * 4096 + m0) * 128;
        #pragma unroll
        for (int p = 0; p < 4; p++) {
            int r = p * 16 + (tid >> 4), c = (tid & 15) * 8;
            *(short8_t*)(dst + r * 128 + c) = *(short8_t*)(Ot + r * 136 + c);
        }
    } else {
        #pragma unroll
        for (int mi = 0; mi < 4; mi++)
            #pragma unroll
            for (int ni = 0; ni < 2; ni++) {
                int ee = e + ni * 16;
                if (ee < 127) {
                    uint2_t u;
                    u[0] = pk_bf16(acc[mi][ni][0], acc[mi][ni][1]);
                    u[1] = pk_bf16(acc[mi][ni][2], acc[mi][ni][3]);
                    *(uint2_t*)(OtT + (1 + ee) * 72 + mi * 16 + lg * 4) = u;
                }
            }
        if (tid < 64) {
            float s = ssqB[tid * 4] + ssqB[tid * 4 + 1] + ssqB[tid * 4 + 2] + ssqB[tid * 4 + 3];
            OtT[tid] = f2bf(sqrtf(1.0f + s));
        }
        __syncthreads();
        int b = m0 >> 10, n0 = m0 & 1023;
        unsigned short* dst = Vt + (h * 4 + b) * 131072 + n0;
        #pragma unroll
        for (int p = 0; p < 4; p++) {
            int d = p * 32 + (tid >> 3), nc = (tid & 7) * 8;
            *(short8_t*)(dst + d * 1024 + nc) = *(short8_t*)(OtT + d * 72 + nc);
        }
    }
}

// ---------------------------------------------------------------------------
// Kernel 2 (v5b): fused Lorentz attention, IN-BLOCK split-KV, 8 waves.
// FIX vs round 8: ALL LDS addressing is absolute from one base pointer L
// (round 8 double-added region bases -> V aliased P and ran out of LDS).
// Layout (absolute byte offsets, 80 KB):
//   K: [half][64 rows][256B]  at 0      + half*16384   (XOR-swizzled)
//   V: [half][128 rows][128B] at 32768  + half*16384   (XOR-swizzled)
//   P: [wave][16 rows][128B]  at 65536  + w*2048       (XOR-swizzled)
// grid = 512 blocks (PROVEN decode h = bid&7), block = 512 = (4 q-subtiles
// of 16 rows) x (2 KV-halves of 512 keys); 8 KV-tiles per wave; 2 blocks/CU
// -> 4 waves/SIMD. Single-buffer + reg-prefetch + 2 barriers/tile + setprio.
// Halves merge in LDS by plain summation (softmax denominator cancels in
// the Lorentz-midpoint rescale; generic beta uses stored log2-max m).
// ---------------------------------------------------------------------------
__global__ __launch_bounds__(512, 4) void k_attn(
    const unsigned short* __restrict__ Qsg, const unsigned short* __restrict__ Kb,
    const unsigned short* __restrict__ Vt,
    const float* __restrict__ beta, const float* __restrict__ gamma,
    float* __restrict__ out, float* __restrict__ tsq)
{
    __shared__ __align__(16) unsigned char lds[81920];
    char*  L   = (char*)lds;
    float* mrg = (float*)lds;           // epilogue: [4][16][132] f32 (33792)
    float* ow  = (float*)(lds + 34816); // epilogue: [4][16][132] f32 (33792)

    const int tid = threadIdx.x, w = tid >> 6, lane = tid & 63;
    const int li = lane & 15, lg = lane >> 4;
    const int qsub = w & 3, half = w >> 2;

    // PROVEN decode: h = bid&7 (all blocks of head h share an XCD)
    const int bid = blockIdx.x;
    const int h = bid & 7;
    const int qt = (bid >> 3) & 15;
    const int b = bid >> 7;
    const int q0 = qt * 64;

    const unsigned short* Qp = Qsg + (h * 4096 + b * 1024) * 128;
    const unsigned short* Kp = Kb  + (h * 4096 + b * 1024) * 128;
    const unsigned short* Vp = Vt  + (h * 4 + b) * 131072;
    const float bet = beta[h];
    const bool beta1 = (bet == 1.0f);
    (void)gamma;

    // staging: threads 0-255 stage half 0, 256-511 stage half 1
    const int hv = tid >> 8, s = tid & 255;
    const int kr = s >> 4, kcl = s & 15;       // K: rows p*16+kr, 16B col kcl
    const int vd = s >> 3, vcl = s & 7;        // V: rows p*32+vd, 16B col vcl
    const unsigned short* Kld = Kp + (hv * 512 + kr) * 128 + kcl * 8;
    const unsigned short* Vld = Vp + vd * 1024 + hv * 512 + vcl * 8;
    // absolute LDS write offsets (+ p*4096 per chunk)
    const int kwb = hv * 16384 + ((kr * 256 + kcl * 16) ^ ((kr & 7) << 4));
    const int vwb = 32768 + hv * 16384 + ((vd * 128 + vcl * 16) ^ ((vd & 7) << 4));

    // absolute per-lane read bases (swizzle XOR is lane-constant; the
    // variable fields XORed in below occupy disjoint bits)
    const int lxor = (li & 7) << 4;
    const int krb = half * 16384 + ((li * 256 + lg * 16) ^ lxor);           // ^ (jf*4096 + kk*64)
    const int vrb = 32768 + half * 16384 + ((li * 128 + lg * 16) ^ lxor);   // ^ (df*2048 + kk2*64)
    const int pwb = 65536 + w * 2048 + ((li * 128 + lg * 8) ^ lxor);        // ^ (jf*32)
    const int prb = 65536 + w * 2048 + ((li * 128 + lg * 16) ^ lxor);       // ^ (kk2*64)

    // persistent Q fragments (16 q-rows per wave, B-operand layout)
    short8_t qf[4];
    const int qrow = q0 + qsub * 16 + li;
    #pragma unroll
    for (int kk = 0; kk < 4; kk++)
        qf[kk] = *(const short8_t*)(Qp + qrow * 128 + kk * 32 + lg * 8);

    float4_t amid[8];
    #pragma unroll
    for (int df = 0; df < 8; df++) amid[df] = (float4_t){0.f, 0.f, 0.f, 0.f};
    float m = beta1 ? 0.0f : -INFINITY;

    short8_t kreg[4], vreg[4];
    // prologue: stage tile 0 of this half
    #pragma unroll
    for (int p = 0; p < 4; p++) {
        kreg[p] = *(const short8_t*)(Kld + p * 2048);
        vreg[p] = *(const short8_t*)(Vld + p * 32768);
    }
    #pragma unroll
    for (int p = 0; p < 4; p++) {
        *(short8_t*)(L + kwb + p * 4096) = kreg[p];
        *(short8_t*)(L + vwb + p * 4096) = vreg[p];
    }
    __syncthreads();

    for (int t = 0; t < 8; t++) {
        // issue next tile's global loads NOW — land during this tile's compute
        if (t < 7) {
            #pragma unroll
            for (int p = 0; p < 4; p++) {
                kreg[p] = *(const short8_t*)(Kld + (t + 1) * 8192 + p * 2048);
                vreg[p] = *(const short8_t*)(Vld + p * 32768 + (t + 1) * 64);
            }
        }
        __builtin_amdgcn_sched_barrier(0);   // keep loads issued up here

        // S^T = K . Qsgn
        float4_t as[4];
        #pragma unroll
        for (int jf = 0; jf < 4; jf++) as[jf] = (float4_t){0.f, 0.f, 0.f, 0.f};
        __builtin_amdgcn_s_setprio(1);
        #pragma unroll
        for (int kk = 0; kk < 4; kk++) {
            #pragma unroll
            for (int jf = 0; jf < 4; jf++) {
                short8_t A = *(short8_t*)(L + ((jf * 4096 + kk * 64) ^ krb));
                as[jf] = MFMA(A, qf[kk], as[jf]);
            }
        }
        __builtin_amdgcn_s_setprio(0);

        if (beta1) {
            // beta==1: P = 1/(z+sqrt(z^2-1)) in (0,1] — bounded, no max
            #pragma unroll
            for (int jf = 0; jf < 4; jf++) {
                float p[4];
                #pragma unroll
                for (int r = 0; r < 4; r++) {
                    float z = fmaxf(-as[jf][r], 1.0f + 1e-6f);
                    float wv = z + __builtin_amdgcn_sqrtf(__builtin_fmaf(z, z, -1.0f));
                    p[r] = __builtin_amdgcn_rcpf(wv);
                }
                uint2_t u; u[0] = pk_bf16(p[0], p[1]); u[1] = pk_bf16(p[2], p[3]);
                *(uint2_t*)(L + ((jf * 32) ^ pwb)) = u;
            }
        } else {
            // generic beta: log2-domain, defer-max; amid stays UNNORMALIZED
            float s2[16];
            float tm = -INFINITY;
            #pragma unroll
            for (int jf = 0; jf < 4; jf++) {
                #pragma unroll
                for (int r = 0; r < 4; r++) {
                    float z = fmaxf(-as[jf][r], 1.0f + 1e-6f);
                    float wv = z + __builtin_amdgcn_sqrtf(__builtin_fmaf(z, z, -1.0f));
                    float sc = -bet * __builtin_amdgcn_logf(wv);
                    s2[jf * 4 + r] = sc;
                    tm = fmaxf(tm, sc);
                }
            }
            tm = fmaxf(tm, __shfl_xor(tm, 16));
            tm = fmaxf(tm, __shfl_xor(tm, 32));
            if (__any(tm > m + 8.0f)) {
                float mn = fmaxf(m, tm);
                float scale = __builtin_amdgcn_exp2f(m - mn);
                #pragma unroll
                for (int df = 0; df < 8; df++)
                    #pragma unroll
                    for (int r = 0; r < 4; r++) amid[df][r] *= scale;
                m = mn;
            }
            #pragma unroll
            for (int jf = 0; jf < 4; jf++) {
                float p0 = __builtin_amdgcn_exp2f(s2[jf * 4 + 0] - m);
                float p1 = __builtin_amdgcn_exp2f(s2[jf * 4 + 1] - m);
                float p2 = __builtin_amdgcn_exp2f(s2[jf * 4 + 2] - m);
                float p3 = __builtin_amdgcn_exp2f(s2[jf * 4 + 3] - m);
                uint2_t u; u[0] = pk_bf16(p0, p1); u[1] = pk_bf16(p2, p3);
                *(uint2_t*)(L + ((jf * 32) ^ pwb)) = u;
            }
        }
        // P writes are wave-local: drain LDS, fence the scheduler
        asm volatile("s_waitcnt lgkmcnt(0)" ::: "memory");
        __builtin_amdgcn_sched_barrier(0);

        // PV: mid^T[d,i] += V^T[d,j] * P^T[j,i]
        __builtin_amdgcn_s_setprio(1);
        #pragma unroll
        for (int kk2 = 0; kk2 < 2; kk2++) {
            short8_t Bp = *(short8_t*)(L + ((kk2 * 64) ^ prb));
            #pragma unroll
            for (int df = 0; df < 8; df++) {
                short8_t A = *(short8_t*)(L + ((df * 2048 + kk2 * 64) ^ vrb));
                amid[df] = MFMA(A, Bp, amid[df]);
            }
        }
        __builtin_amdgcn_s_setprio(0);

        // restage the single buffer (loads landed during compute)
        if (t < 7) {
            __syncthreads();   // A: all waves' K/V/P reads done
            #pragma unroll
            for (int p = 0; p < 4; p++) {
                *(short8_t*)(L + kwb + p * 4096) = kreg[p];
                *(short8_t*)(L + vwb + p * 4096) = vreg[p];
            }
            __syncthreads();   // B: new tile visible
        }
    }

    // ---- in-LDS cross-half merge (exact) ----
    __syncthreads();   // all K/V/P reads done -> LDS reusable
    if (half == 1) {
        float* mb = mrg + qsub * 2112;
        #pragma unroll
        for (int df = 0; df < 8; df++)
            #pragma unroll
            for (int r = 0; r < 4; r++)
                mb[li * 132 + df * 16 + lg * 4 + r] = amid[df][r];
        if (lg == 0) mb[li * 132 + 128] = m;
    }
    __syncthreads();
    if (half == 1) return;   // no further barriers below

    {
        float* mb = mrg + qsub * 2112;
        if (beta1) {
            #pragma unroll
            for (int df = 0; df < 8; df++)
                #pragma unroll
                for (int r = 0; r < 4; r++)
                    amid[df][r] += mb[li * 132 + df * 16 + lg * 4 + r];
        } else {
            float m1v = mb[li * 132 + 128];
            float mN = fmaxf(m, m1v);
            float s0 = __builtin_amdgcn_exp2f(m - mN);
            float s1 = __builtin_amdgcn_exp2f(m1v - mN);
            #pragma unroll
            for (int df = 0; df < 8; df++)
                #pragma unroll
                for (int r = 0; r < 4; r++)
                    amid[df][r] = amid[df][r] * s0 + mb[li * 132 + df * 16 + lg * 4 + r] * s1;
        }
    }

    // epilogue: Lorentz-midpoint rescale (scale-invariant -> no lsum needed)
    float ssq = 0.0f;
    #pragma unroll
    for (int df = 0; df < 8; df++)
        #pragma unroll
        for (int r = 0; r < 4; r++) ssq += amid[df][r] * amid[df][r];
    ssq += __shfl_xor(ssq, 16);
    ssq += __shfl_xor(ssq, 32);
    float tmid = __shfl(amid[0][0], li);           // mid[d=0] for this lane's i
    float denom = fmaxf(2.0f * tmid * tmid - ssq, 1e-12f);  // -<m,m>_L (unnormalized)
    float rs = 1.0f / sqrtf(denom);

    #pragma unroll
    for (int df = 0; df < 8; df++) {
        #pragma unroll
        for (int r = 0; r < 4; r++)
            ow[qsub * 2112 + li * 132 + df * 16 + lg * 4 + r] = amid[df][r] * rs;
    }
    asm volatile("s_waitcnt lgkmcnt(0)" ::: "memory");
    __builtin_amdgcn_sched_barrier(0);

    #pragma unroll
    for (int i = 0; i < 16; i++) {
        int n = q0 + qsub * 16 + i;
        float v0 = ow[qsub * 2112 + i * 132 + lane];
        float v1 = ow[qsub * 2112 + i * 132 + 64 + lane];
        float* orow = out + (b * 1024 + n) * 1017;
        if (lane == 0) tsq[h * 4096 + b * 1024 + n] = v0 * v0;
        else           orow[h * 127 + lane] = v0;        // comp = 1 + h*127 + (d-1)
        orow[h * 127 + 64 + lane] = v1;
    }
}

// ---------------------------------------------------------------------------
// Kernel 3: output time coordinate from per-head t^2
// ---------------------------------------------------------------------------
__global__ __launch_bounds__(256) void k_time(const float* __restrict__ tsq,
                                              float* __restrict__ out)
{
    int mrow = blockIdx.x * 256 + threadIdx.x;
    float s = 0.0f;
    #pragma unroll
    for (int h = 0; h < 8; h++) s += tsq[h * 4096 + mrow];
    out[mrow * 1017] = sqrtf(fmaxf(s - 7.0f, 1e-6f));
}

extern "C" void kernel_launch(void* const* d_in, const int* in_sizes, int n_in,
                              void* d_out, int out_size, void* d_ws, size_t ws_size,
                              hipStream_t stream)
{
    const float* x    = (const float*)d_in[0];
    const float* Wq   = (const float*)d_in[1];
    const float* bq   = (const float*)d_in[2];
    const float* Wk   = (const float*)d_in[3];
    const float* bk   = (const float*)d_in[4];
    const float* Wv   = (const float*)d_in[5];
    const float* bv   = (const float*)d_in[6];
    const float* beta = (const float*)d_in[7];
    const float* gam  = (const float*)d_in[8];
    float* out = (float*)d_out;

    unsigned char* ws = (unsigned char*)d_ws;
    unsigned short* Qs = (unsigned short*)(ws);              //  8 MB
    unsigned short* Kb = (unsigned short*)(ws + 8388608);    //  8 MB
    unsigned short* Vt = (unsigned short*)(ws + 16777216);   //  8 MB
    float*          ts = (float*)(ws + 25165824);            // 128 KB

    k_proj<<<dim3(64, 8, 3), 256, 0, stream>>>(x, Wq, bq, Wk, bk, Wv, bv, Qs, Kb, Vt);
    k_attn<<<dim3(512), 512, 0, stream>>>(Qs, Kb, Vt, beta, gam, out, ts);
    k_time<<<dim3(16), 256, 0, stream>>>(ts, out);
}